// Round 12
// baseline (1336.729 us; speedup 1.0000x reference)
//
#include <hip/hip_runtime.h>
#include <math.h>

#define B_     128
#define L_     100
#define HID_   256
#define IND_   160
#define NCLASS 19
#define CAPD   16
#define NI     1600      // L_ * NUM_CAPS
#define OD     304       // NCLASS * CAPD
#define ENTITY 68

#define SLDS   24        // LDS-resident weight slices (q0's p=0..23), 96KB (R9 optimum)
#define NBT    4         // batch chunks in routing (32 b each)
#define BLH    32        // batch per routing block

typedef _Float16 half2_t __attribute__((ext_vector_type(2)));

__device__ inline half2_t as_h2(unsigned u) {
    union { unsigned u; half2_t h; } x; x.u = u; return x.h;
}
__device__ inline unsigned pack2(float a, float b) {
    union { unsigned u; half2_t h; } x;
    x.h = (half2_t){ (_Float16)a, (_Float16)b };   // RTN converts
    return x.u;
}
__device__ inline float fdot2_(unsigned w, unsigned h, float acc) {
#if __has_builtin(__builtin_amdgcn_fdot2)
    return __builtin_amdgcn_fdot2(as_h2(w), as_h2(h), acc, false);
#else
    half2_t wh = as_h2(w), hh = as_h2(h);
    acc = fmaf((float)wh.x, (float)hh.x, acc);
    return fmaf((float)wh.y, (float)hh.y, acc);
#endif
}

// ---------------------------------------------------------------------------
// Phase 0 (fused prep): embedding gather + wih pack + whh pack in ONE kernel.
// ---------------------------------------------------------------------------
__global__ void prep16(const int* __restrict__ word, const int* __restrict__ tag,
                       const int* __restrict__ pos1, const int* __restrict__ pos2,
                       const float* __restrict__ we, const float* __restrict__ te,
                       const float* __restrict__ p1e, const float* __restrict__ p2e,
                       const float* __restrict__ wihf, const float* __restrict__ wihb,
                       const float* __restrict__ whhf, const float* __restrict__ whhb,
                       unsigned* __restrict__ emb16, unsigned* __restrict__ wih16,
                       unsigned* __restrict__ wp16)
{
    int gid = blockIdx.x * 256 + threadIdx.x;
    if (gid < 1024000) {                       // embedding gather
        int idx = gid;
        int bt = idx / 80;
        int kp = idx - bt * 80;
        int k  = 2 * kp;
        float v0, v1;
        if (k < 100)      { const float* p = we  + word[bt] * 100 + k;         v0 = p[0]; v1 = p[1]; }
        else if (k < 120) { const float* p = te  + tag[bt]  * 20 + (k - 100);  v0 = p[0]; v1 = p[1]; }
        else if (k < 140) { const float* p = p1e + pos1[bt] * 20 + (k - 120);  v0 = p[0]; v1 = p[1]; }
        else              { const float* p = p2e + pos2[bt] * 20 + (k - 140);  v0 = p[0]; v1 = p[1]; }
        emb16[idx] = pack2(v0, v1);
    } else if (gid < 1187840) {                // input-gate weight pack
        int idx = gid - 1024000;
        int dir = idx / 81920;
        int rem = idx - dir * 81920;
        int kp  = rem >> 10;
        int gj  = rem & 1023;
        const float* w = dir ? wihb : wihf;
        const float* row = w + (size_t)gj * IND_ + 2 * kp;
        wih16[idx] = pack2(row[0], row[1]);
    } else if (gid < 1449984) {                // recurrent weight pack
        int idx = gid - 1187840;
        int g   = idx & 3;
        int h   = (idx >> 2) & 255;
        int p   = (idx >> 10) & 127;
        int dir = idx >> 17;
        const float* whh = dir ? whhb : whhf;
        const float* row = whh + (size_t)(g * 256 + h) * HID_;
        wp16[idx] = pack2(row[2 * p], row[2 * p + 1]);
    }
}

// ---------------------------------------------------------------------------
// Phase 1: input-gate GEMM in f16 dot2.
// xg layout: [dir][t][bpair(64)][gj(1024)][2]
// ---------------------------------------------------------------------------
__global__ void __launch_bounds__(256) gemm_xg16(
    const unsigned* __restrict__ emb16, const unsigned* __restrict__ wih16,
    const float* __restrict__ bihf, const float* __restrict__ bhhf,
    const float* __restrict__ bihb, const float* __restrict__ bhhb,
    float* __restrict__ xg)
{
    int gt  = blockIdx.x;
    int t   = blockIdx.y;
    int dir = blockIdx.z;
    const unsigned* wbase = wih16 + (size_t)dir * 81920;
    const float* bi = dir ? bihb : bihf;
    const float* bh = dir ? bhhb : bhhf;
    int gj0 = gt * 128;

    __shared__ unsigned wsh[16][132];   // [kp][gj], padded
    __shared__ unsigned esh[16][132];   // [kp][b],  padded

    int tid = threadIdx.x;
    int tx = tid & 15, ty = tid >> 4;

    float acc[8][8];
    #pragma unroll
    for (int i = 0; i < 8; ++i)
        #pragma unroll
        for (int j = 0; j < 8; ++j) acc[i][j] = 0.f;

    for (int kp0 = 0; kp0 < 80; kp0 += 16) {
        __syncthreads();
        #pragma unroll
        for (int m = 0; m < 8; ++m) {
            int e = m * 256 + tid;          // 0..2047
            int kw = e >> 7, gw = e & 127;
            wsh[kw][gw] = wbase[(kp0 + kw) * 1024 + gj0 + gw];
            int ke = e & 15, ge = e >> 4;
            esh[ke][ge] = emb16[((size_t)ge * L_ + t) * 80 + kp0 + ke];
        }
        __syncthreads();
        #pragma unroll
        for (int kp = 0; kp < 16; ++kp) {
            unsigned wv[8], ev[8];
            #pragma unroll
            for (int q = 0; q < 8; ++q) wv[q] = wsh[kp][ty * 8 + q];
            #pragma unroll
            for (int q = 0; q < 8; ++q) ev[q] = esh[kp][tx * 8 + q];
            #pragma unroll
            for (int i = 0; i < 8; ++i)
                #pragma unroll
                for (int j = 0; j < 8; ++j) acc[i][j] = fdot2_(wv[i], ev[j], acc[i][j]);
        }
    }
    #pragma unroll
    for (int i = 0; i < 8; ++i) {
        int gj = gj0 + ty * 8 + i;
        float bias = bi[gj] + bh[gj];
        #pragma unroll
        for (int j = 0; j < 8; ++j) {
            int b = tx * 8 + j;
            xg[((((size_t)dir * L_ + t) * 64 + (b >> 1)) * 1024 + gj) * 2 + (b & 1)]
                = acc[i][j] + bias;
        }
    }
}

// ---------------------------------------------------------------------------
// Phase 2: BiLSTM scan — R9 configuration exactly (SLDS=24; R11's 28
// regressed: barrier-governed, extra LDS work landed on the epilogue wave).
// ---------------------------------------------------------------------------
__global__ void __launch_bounds__(1024, 4) lstm_scan_s(
    const float* __restrict__ xg, const uint4* __restrict__ wp16,
    float* __restrict__ xf2, float* __restrict__ xb2)
{
    int blk = blockIdx.x;
    int dir = blk >> 6;            // 0..1
    int bp  = blk & 63;            // b-pair index
    int tid = threadIdx.x;
    int h   = tid & 255;           // hidden unit
    int q   = tid >> 8;            // k-quarter 0..3 (wave-uniform)

    const uint4* wt = wp16 + (size_t)dir * 128 * 256;   // [p][hid] uint4
    float* xo = dir ? xb2 : xf2;

    __shared__ uint2 hA[128];            // [p] = {bs0 f16x2, bs1 f16x2}
    __shared__ uint2 hB[128];
    __shared__ float pbuf[4][8][256];    // [q][gate*2+bs][h], 32KB
    __shared__ uint4 wlds[SLDS][256];    // q0's p=0..SLDS-1, 96KB

    for (int m = q; m < SLDS; m += 4)
        wlds[m][h] = wt[m * 256 + h];

    if (tid < 256) ((unsigned*)hA)[tid] = 0u;
    float c0 = 0.f, c1 = 0.f;            // live only in q==0 threads
    __syncthreads();

    int pq0  = q * 32;
    int sbeg = (q == 0) ? SLDS : pq0;
    int send = pq0 + 32;

    for (int t = 0; t < L_; ++t) {
        int slot = dir ? (L_ - 1 - t) : t;
        const uint2* hp = (t & 1) ? hB : hA;
        unsigned*    hw = (unsigned*)((t & 1) ? hA : hB);

        float2 gI, gF, gG, gO;
        if (q == 0) {
            const float* xbase = xg + (((size_t)dir * L_ + slot) * 64 + bp) * 2048;
            gI = *(const float2*)(xbase + (0 * 256 + h) * 2);
            gF = *(const float2*)(xbase + (1 * 256 + h) * 2);
            gG = *(const float2*)(xbase + (2 * 256 + h) * 2);
            gO = *(const float2*)(xbase + (3 * 256 + h) * 2);
        }

        float aI0=0.f, aI1=0.f, aF0=0.f, aF1=0.f;
        float aG0=0.f, aG1=0.f, aO0=0.f, aO1=0.f;

        #pragma unroll 8
        for (int p = sbeg; p < send; ++p) {
            uint4 w4 = wt[p * 256 + h];   // coalesced 1KB/wave from L2
            uint2 hb = hp[p];             // broadcast b64
            aI0 = fdot2_(w4.x, hb.x, aI0); aI1 = fdot2_(w4.x, hb.y, aI1);
            aF0 = fdot2_(w4.y, hb.x, aF0); aF1 = fdot2_(w4.y, hb.y, aF1);
            aG0 = fdot2_(w4.z, hb.x, aG0); aG1 = fdot2_(w4.z, hb.y, aG1);
            aO0 = fdot2_(w4.w, hb.x, aO0); aO1 = fdot2_(w4.w, hb.y, aO1);
        }
        if (q == 0) {
            #pragma unroll 8
            for (int p = 0; p < SLDS; ++p) {
                uint4 w4 = wlds[p][h];
                uint2 hb = hp[p];
                aI0 = fdot2_(w4.x, hb.x, aI0); aI1 = fdot2_(w4.x, hb.y, aI1);
                aF0 = fdot2_(w4.y, hb.x, aF0); aF1 = fdot2_(w4.y, hb.y, aF1);
                aG0 = fdot2_(w4.z, hb.x, aG0); aG1 = fdot2_(w4.z, hb.y, aG1);
                aO0 = fdot2_(w4.w, hb.x, aO0); aO1 = fdot2_(w4.w, hb.y, aO1);
            }
        }

        pbuf[q][0][h] = aI0; pbuf[q][1][h] = aI1;
        pbuf[q][2][h] = aF0; pbuf[q][3][h] = aF1;
        pbuf[q][4][h] = aG0; pbuf[q][5][h] = aG1;
        pbuf[q][6][h] = aO0; pbuf[q][7][h] = aO1;
        __syncthreads();

        if (q == 0) {
            float sI0 = pbuf[0][0][h] + pbuf[1][0][h] + pbuf[2][0][h] + pbuf[3][0][h] + gI.x;
            float sI1 = pbuf[0][1][h] + pbuf[1][1][h] + pbuf[2][1][h] + pbuf[3][1][h] + gI.y;
            float sF0 = pbuf[0][2][h] + pbuf[1][2][h] + pbuf[2][2][h] + pbuf[3][2][h] + gF.x;
            float sF1 = pbuf[0][3][h] + pbuf[1][3][h] + pbuf[2][3][h] + pbuf[3][3][h] + gF.y;
            float sG0 = pbuf[0][4][h] + pbuf[1][4][h] + pbuf[2][4][h] + pbuf[3][4][h] + gG.x;
            float sG1 = pbuf[0][5][h] + pbuf[1][5][h] + pbuf[2][5][h] + pbuf[3][5][h] + gG.y;
            float sO0 = pbuf[0][6][h] + pbuf[1][6][h] + pbuf[2][6][h] + pbuf[3][6][h] + gO.x;
            float sO1 = pbuf[0][7][h] + pbuf[1][7][h] + pbuf[2][7][h] + pbuf[3][7][h] + gO.y;

            float i0 = 1.f / (1.f + expf(-sI0));
            float f0 = 1.f / (1.f + expf(-sF0));
            float g0 = tanhf(sG0);
            float o0 = 1.f / (1.f + expf(-sO0));
            c0 = f0 * c0 + i0 * g0;
            float hv0 = o0 * tanhf(c0);

            float i1 = 1.f / (1.f + expf(-sI1));
            float f1 = 1.f / (1.f + expf(-sF1));
            float g1 = tanhf(sG1);
            float o1 = 1.f / (1.f + expf(-sO1));
            c1 = f1 * c1 + i1 * g1;
            float hv1 = o1 * tanhf(c1);

            float n0 = __shfl_xor(hv0, 1);
            float n1 = __shfl_xor(hv1, 1);
            hw[h] = (h & 1) ? pack2(n1, hv1)
                            : pack2(hv0, n0);
            float* xp = xo + ((size_t)slot * 64 + bp) * 512 + h * 2;
            xp[0] = hv0; xp[1] = hv1;
        }
        __syncthreads();
    }
}

// remap [slot][bp][hid*2+bs] -> x[slot][hid][b], summing directions.
__global__ void x_add(const float* __restrict__ xf2, const float* __restrict__ xb2,
                      float* __restrict__ x)
{
    int idx = blockIdx.x * 256 + threadIdx.x;   // exactly L_*HID_*B_ threads
    int b    = idx & 127;
    int j    = (idx >> 7) & 255;
    int slot = idx >> 15;
    int src  = ((slot * 64 + (b >> 1)) * 512) + j * 2 + (b & 1);
    x[idx] = xf2[src] + xb2[src];
}

// ---------------------------------------------------------------------------
// Phase 2.5: pack W_caps to f16 c-pairs (unchanged).
// ---------------------------------------------------------------------------
__global__ void wc_pack16(const float* __restrict__ W, unsigned* __restrict__ wc)
{
    int gid = blockIdx.x * 256 + threadIdx.x;   // exactly 1600*8*304 threads
    int od  = gid % OD;
    int rest = gid / OD;
    int cp  = rest & 7;
    int i   = rest >> 3;
    float a = W[((size_t)i * 16 + 2 * cp) * OD + od];
    float b = W[((size_t)i * 16 + 2 * cp + 1) * OD + od];
    wc[gid] = pack2(a, b);
}

// ---------------------------------------------------------------------------
// Phase 3: attention chain (unchanged).
// ---------------------------------------------------------------------------
__global__ void compute_he2(const int* __restrict__ pos1, const int* __restrict__ pos2,
                            const float* __restrict__ x, float* __restrict__ he)
{
    int j = blockIdx.x, b = threadIdx.x;
    int e1 = 0, e2 = 0;
    for (int l = L_ - 1; l >= 0; --l) if (pos1[b * L_ + l] == ENTITY) e1 = l;
    for (int l = L_ - 1; l >= 0; --l) if (pos2[b * L_ + l] == ENTITY) e2 = l;
    he[j * B_ + b] = x[((size_t)e1 * HID_ + j) * B_ + b] + x[((size_t)e2 * HID_ + j) * B_ + b];
}

__global__ void att_logits2(const float* __restrict__ x, const float* __restrict__ he,
                            float* __restrict__ lp)
{
    int l = blockIdx.x, jc = blockIdx.y, b = threadIdx.x;
    int j0 = jc * 32;
    float acc = 0.f;
    #pragma unroll
    for (int jj = 0; jj < 32; ++jj) {
        int j = j0 + jj;
        acc = fmaf(x[((size_t)l * HID_ + j) * B_ + b], he[j * B_ + b], acc);
    }
    lp[((size_t)jc * L_ + l) * B_ + b] = acc;
}

__global__ void att_softmax2(const float* __restrict__ lp, float* __restrict__ att)
{
    int b = blockIdx.x, l = threadIdx.x;    // 128 blocks x 128 threads
    float val = 0.f;
    if (l < L_) {
        #pragma unroll
        for (int jc = 0; jc < 8; ++jc) val += lp[((size_t)jc * L_ + l) * B_ + b];
    }
    __shared__ float red[128];
    red[l] = (l < L_) ? val : -1e30f;
    __syncthreads();
    for (int off = 64; off > 0; off >>= 1) {
        if (l < off) red[l] = fmaxf(red[l], red[l + off]);
        __syncthreads();
    }
    float m = red[0];
    __syncthreads();
    float e = (l < L_) ? expf(val - m) : 0.f;
    red[l] = e;
    __syncthreads();
    for (int off = 64; off > 0; off >>= 1) {
        if (l < off) red[l] += red[l + off];
        __syncthreads();
    }
    float inv = 1.f / red[0];
    if (l < L_) att[l * B_ + b] = e * inv;
}

__global__ void u_squash16(const float* __restrict__ x, unsigned* __restrict__ u16)
{
    int i = blockIdx.x, b = threadIdx.x;
    int l = i >> 4, cap = i & 15;
    float vals[16]; float n2 = 0.f;
    #pragma unroll
    for (int c2 = 0; c2 < 16; ++c2) {
        float v = x[((size_t)l * HID_ + cap * 16 + c2) * B_ + b];
        vals[c2] = v; n2 = fmaf(v, v, n2);
    }
    float f = (n2 / (1.f + n2)) / sqrtf(n2 + 1e-9f);
    #pragma unroll
    for (int cp = 0; cp < 8; ++cp)
        u16[((size_t)i * B_ + b) * 8 + cp] = pack2(vals[2 * cp] * f, vals[2 * cp + 1] * f);
}

// ---------------------------------------------------------------------------
// Phase 4: routing. NEW: bt-loop inside the block (grid 100 x NBT=4, 32 b
// per block): each w2 load is reused by 32 batch columns instead of 16,
// cutting Wc16 re-read traffic per pass 124MB -> 62MB.
// ---------------------------------------------------------------------------
__global__ void __launch_bounds__(320) s_pass16(
    const unsigned* __restrict__ u16, const unsigned* __restrict__ Wc16,
    const float* __restrict__ bb, const float* __restrict__ br, int first,
    const float* __restrict__ att, float* __restrict__ partial)
{
    int ic = blockIdx.x, bt = blockIdx.y;
    int i0 = ic * 16, b0 = bt * BLH;
    __shared__ float C[BLH][16][20];   // [bl][il][o], padded (40KB)
    int tid = threadIdx.x;
    for (int e = tid; e < BLH * 16; e += 320) {
        int bl = e >> 4, il = e & 15;
        int b = b0 + bl, i = i0 + il;
        const float* bbp = first ? (br + (size_t)i * NCLASS)
                                 : (bb + ((size_t)b * NI + i) * NCLASS);
        float m = bbp[0];
        #pragma unroll
        for (int o = 1; o < NCLASS; ++o) m = fmaxf(m, bbp[o]);
        float s = 0.f; float e2[NCLASS];
        #pragma unroll
        for (int o = 0; o < NCLASS; ++o) { e2[o] = expf(bbp[o] - m); s += e2[o]; }
        float al = att[(i >> 4) * B_ + b] / s;
        #pragma unroll
        for (int o = 0; o < NCLASS; ++o) C[bl][il][o] = e2[o] * al;
    }
    __syncthreads();
    if (tid >= OD) return;
    int od = tid, o = od >> 4;
    float acc[BLH];
    #pragma unroll
    for (int bl = 0; bl < BLH; ++bl) acc[bl] = 0.f;
    for (int il = 0; il < 16; ++il) {
        int i = i0 + il;
        const unsigned* wp = Wc16 + (size_t)i * 8 * OD + od;
        unsigned w2[8];
        #pragma unroll
        for (int cp = 0; cp < 8; ++cp) w2[cp] = wp[cp * OD];     // coalesced over od
        const unsigned* up = u16 + ((size_t)i * B_ + b0) * 8;    // uniform -> s_load
        #pragma unroll
        for (int bl = 0; bl < BLH; ++bl) {
            float uh = 0.f;
            #pragma unroll
            for (int cp = 0; cp < 8; ++cp) uh = fdot2_(up[bl * 8 + cp], w2[cp], uh);
            acc[bl] = fmaf(C[bl][il][o], uh, acc[bl]);
        }
    }
    #pragma unroll
    for (int bl = 0; bl < BLH; ++bl)
        partial[((size_t)ic * B_ + b0 + bl) * OD + od] = acc[bl];
}

// fused: sum partials over ic, squash to v, optional capsule-length output
__global__ void __launch_bounds__(320) sreduce_squash(
    const float* __restrict__ partial, float* __restrict__ v,
    float* __restrict__ out, int write_out)
{
    int b = blockIdx.x;            // 128 blocks
    int od = threadIdx.x;          // 320 threads, od < OD active
    if (od >= OD) return;
    float acc = 0.f;
    for (int ic = 0; ic < 100; ++ic) acc += partial[((size_t)ic * B_ + b) * OD + od];
    float n2 = acc * acc;
    n2 += __shfl_xor(n2, 1); n2 += __shfl_xor(n2, 2);
    n2 += __shfl_xor(n2, 4); n2 += __shfl_xor(n2, 8);
    float f = (n2 / (1.f + n2)) / sqrtf(n2 + 1e-9f);
    float vv = acc * f;
    v[(size_t)b * OD + od] = vv;
    if (write_out) {
        float n2v = vv * vv;
        n2v += __shfl_xor(n2v, 1); n2v += __shfl_xor(n2v, 2);
        n2v += __shfl_xor(n2v, 4); n2v += __shfl_xor(n2v, 8);
        if ((od & 15) == 0) out[b * NCLASS + (od >> 4)] = sqrtf(n2v + 1e-9f);
    }
}

__global__ void __launch_bounds__(320) bb_pass16(
    const unsigned* __restrict__ u16, const unsigned* __restrict__ Wc16,
    const float* __restrict__ v, float* __restrict__ bb,
    const float* __restrict__ br, int first)
{
    int ic = blockIdx.x, bt = blockIdx.y;
    int i0 = ic * 16, b0 = bt * BLH;
    int tid = threadIdx.x;
    if (tid >= OD) return;
    int od = tid, o = od >> 4, d = od & 15;
    float vv[BLH];
    #pragma unroll
    for (int bl = 0; bl < BLH; ++bl) vv[bl] = v[(size_t)(b0 + bl) * OD + od];
    for (int il = 0; il < 16; ++il) {
        int i = i0 + il;
        const unsigned* wp = Wc16 + (size_t)i * 8 * OD + od;
        unsigned w2[8];
        #pragma unroll
        for (int cp = 0; cp < 8; ++cp) w2[cp] = wp[cp * OD];
        const unsigned* up = u16 + ((size_t)i * B_ + b0) * 8;
        #pragma unroll
        for (int bl = 0; bl < BLH; ++bl) {
            float uh = 0.f;
            #pragma unroll
            for (int cp = 0; cp < 8; ++cp) uh = fdot2_(up[bl * 8 + cp], w2[cp], uh);
            float p = uh * vv[bl];
            p += __shfl_xor(p, 1);
            p += __shfl_xor(p, 2);
            p += __shfl_xor(p, 4);
            p += __shfl_xor(p, 8);
            if (d == 0) {
                size_t off = ((size_t)(b0 + bl) * NI + i) * NCLASS + o;
                bb[off] = (first ? br[(size_t)i * NCLASS + o] : bb[off]) + p;
            }
        }
    }
}

// ---------------------------------------------------------------------------
extern "C" void kernel_launch(void* const* d_in, const int* in_sizes, int n_in,
                              void* d_out, int out_size, void* d_ws, size_t ws_size,
                              hipStream_t stream)
{
    (void)in_sizes; (void)n_in; (void)out_size; (void)ws_size;
    const int*   word = (const int*)d_in[0];
    const int*   tag  = (const int*)d_in[1];
    const int*   pos1 = (const int*)d_in[2];
    const int*   pos2 = (const int*)d_in[3];
    const float* we   = (const float*)d_in[4];
    const float* te   = (const float*)d_in[5];
    const float* p1e  = (const float*)d_in[6];
    const float* p2e  = (const float*)d_in[7];
    const float* wihf = (const float*)d_in[8];
    const float* whhf = (const float*)d_in[9];
    const float* bihf = (const float*)d_in[10];
    const float* bhhf = (const float*)d_in[11];
    const float* wihb = (const float*)d_in[12];
    const float* whhb = (const float*)d_in[13];
    const float* bihb = (const float*)d_in[14];
    const float* bhhb = (const float*)d_in[15];
    const float* Wc   = (const float*)d_in[16];
    const float* br   = (const float*)d_in[17];

    float* wsp = (float*)d_ws;
    // packed-input region (old emb area, 2,048,000 floats):
    unsigned* emb16 = (unsigned*)wsp;                    // 1,024,000 uints
    unsigned* wih16 = (unsigned*)(wsp + 1024000);        //   163,840 uints
    unsigned* wp16  = (unsigned*)(wsp + 1024000 + 163840); // 262,144 uints
    float* xg  = wsp + 2048000;                // 26,214,400
    float* xf  = xg + 26214400;                //  3,276,800
    float* xb  = xf + 3276800;                 //  3,276,800
    float* he  = xb + 3276800;                 //     32,768
    float* att = he + 32768;                   //     12,800
    // packed f16 W_caps spans xf and part of xb (both dead after x_add)
    unsigned* Wc16 = (unsigned*)xf;            //  3,891,200 uints
    float*    lp   = xf + 3891200;             //    102,400 (xb tail, free)
    // post-scan buffers alias the (dead-after-scan) xg region
    float*    x    = xg;                       //  3,276,800
    unsigned* u16  = (unsigned*)(xg + 3276800);//  1,638,400 uints
    float*    bb   = xg + 6553600;             //  3,891,200
    float*    part = xg + 10444800;            //  3,891,200
    float*    s    = xg + 14336000;            //     38,912 (unused now)
    float*    v    = s + 38912;                //     38,912
    float*    out  = (float*)d_out;

    prep16<<<5665, 256, 0, stream>>>(word, tag, pos1, pos2, we, te, p1e, p2e,
                                     wihf, wihb, whhf, whhb, emb16, wih16, wp16);
    gemm_xg16<<<dim3(8, 100, 2), 256, 0, stream>>>(emb16, wih16, bihf, bhhf, bihb, bhhb, xg);
    lstm_scan_s<<<128, 1024, 0, stream>>>(xg, (const uint4*)wp16, xf, xb);
    x_add<<<12800, 256, 0, stream>>>(xf, xb, x);
    wc_pack16<<<15200, 256, 0, stream>>>(Wc, Wc16);   // after x_add: xf/xb dead
    compute_he2<<<256, 128, 0, stream>>>(pos1, pos2, x, he);
    att_logits2<<<dim3(100, 8), 128, 0, stream>>>(x, he, lp);
    att_softmax2<<<128, 128, 0, stream>>>(lp, att);
    u_squash16<<<1600, 128, 0, stream>>>(x, u16);
    for (int it = 0; it < 3; ++it) {
        s_pass16<<<dim3(100, NBT), 320, 0, stream>>>(u16, Wc16, bb, br, it == 0, att, part);
        sreduce_squash<<<128, 320, 0, stream>>>(part, v, out, (it == 2) ? 1 : 0);
        if (it < 2) bb_pass16<<<dim3(100, NBT), 320, 0, stream>>>(u16, Wc16, v, bb, br, it == 0);
    }
}

// Round 13
// 1077.591 us; speedup vs baseline: 1.2405x; 1.2405x over previous
//
#include <hip/hip_runtime.h>
#include <math.h>

#define B_     128
#define L_     100
#define HID_   256
#define IND_   160
#define NCLASS 19
#define CAPD   16
#define NI     1600      // L_ * NUM_CAPS
#define OD     304       // NCLASS * CAPD
#define ENTITY 68

#define SLDS   24        // LDS-resident weight slices (q0's p=0..23), 96KB (R9 optimum)
#define NBT    8         // batch chunks in routing (16 b each) — R11/R9 optimum
#define BLH    16        // batch per routing block (R12's 32 regressed: reg pressure)

typedef _Float16 half2_t __attribute__((ext_vector_type(2)));

__device__ inline half2_t as_h2(unsigned u) {
    union { unsigned u; half2_t h; } x; x.u = u; return x.h;
}
__device__ inline unsigned pack2(float a, float b) {
    union { unsigned u; half2_t h; } x;
    x.h = (half2_t){ (_Float16)a, (_Float16)b };   // RTN converts
    return x.u;
}
__device__ inline float fdot2_(unsigned w, unsigned h, float acc) {
#if __has_builtin(__builtin_amdgcn_fdot2)
    return __builtin_amdgcn_fdot2(as_h2(w), as_h2(h), acc, false);
#else
    half2_t wh = as_h2(w), hh = as_h2(h);
    acc = fmaf((float)wh.x, (float)hh.x, acc);
    return fmaf((float)wh.y, (float)hh.y, acc);
#endif
}

// ---------------------------------------------------------------------------
// Phase 0 (fused prep): embedding gather + wih pack + whh pack in ONE kernel.
// ---------------------------------------------------------------------------
__global__ void prep16(const int* __restrict__ word, const int* __restrict__ tag,
                       const int* __restrict__ pos1, const int* __restrict__ pos2,
                       const float* __restrict__ we, const float* __restrict__ te,
                       const float* __restrict__ p1e, const float* __restrict__ p2e,
                       const float* __restrict__ wihf, const float* __restrict__ wihb,
                       const float* __restrict__ whhf, const float* __restrict__ whhb,
                       unsigned* __restrict__ emb16, unsigned* __restrict__ wih16,
                       unsigned* __restrict__ wp16)
{
    int gid = blockIdx.x * 256 + threadIdx.x;
    if (gid < 1024000) {                       // embedding gather
        int idx = gid;
        int bt = idx / 80;
        int kp = idx - bt * 80;
        int k  = 2 * kp;
        float v0, v1;
        if (k < 100)      { const float* p = we  + word[bt] * 100 + k;         v0 = p[0]; v1 = p[1]; }
        else if (k < 120) { const float* p = te  + tag[bt]  * 20 + (k - 100);  v0 = p[0]; v1 = p[1]; }
        else if (k < 140) { const float* p = p1e + pos1[bt] * 20 + (k - 120);  v0 = p[0]; v1 = p[1]; }
        else              { const float* p = p2e + pos2[bt] * 20 + (k - 140);  v0 = p[0]; v1 = p[1]; }
        emb16[idx] = pack2(v0, v1);
    } else if (gid < 1187840) {                // input-gate weight pack
        int idx = gid - 1024000;
        int dir = idx / 81920;
        int rem = idx - dir * 81920;
        int kp  = rem >> 10;
        int gj  = rem & 1023;
        const float* w = dir ? wihb : wihf;
        const float* row = w + (size_t)gj * IND_ + 2 * kp;
        wih16[idx] = pack2(row[0], row[1]);
    } else if (gid < 1449984) {                // recurrent weight pack
        int idx = gid - 1187840;
        int g   = idx & 3;
        int h   = (idx >> 2) & 255;
        int p   = (idx >> 10) & 127;
        int dir = idx >> 17;
        const float* whh = dir ? whhb : whhf;
        const float* row = whh + (size_t)(g * 256 + h) * HID_;
        wp16[idx] = pack2(row[2 * p], row[2 * p + 1]);
    }
}

// ---------------------------------------------------------------------------
// Phase 1: input-gate GEMM in f16 dot2.
// xg layout: [dir][t][bpair(64)][gj(1024)][2]
// ---------------------------------------------------------------------------
__global__ void __launch_bounds__(256) gemm_xg16(
    const unsigned* __restrict__ emb16, const unsigned* __restrict__ wih16,
    const float* __restrict__ bihf, const float* __restrict__ bhhf,
    const float* __restrict__ bihb, const float* __restrict__ bhhb,
    float* __restrict__ xg)
{
    int gt  = blockIdx.x;
    int t   = blockIdx.y;
    int dir = blockIdx.z;
    const unsigned* wbase = wih16 + (size_t)dir * 81920;
    const float* bi = dir ? bihb : bihf;
    const float* bh = dir ? bhhb : bhhf;
    int gj0 = gt * 128;

    __shared__ unsigned wsh[16][132];   // [kp][gj], padded
    __shared__ unsigned esh[16][132];   // [kp][b],  padded

    int tid = threadIdx.x;
    int tx = tid & 15, ty = tid >> 4;

    float acc[8][8];
    #pragma unroll
    for (int i = 0; i < 8; ++i)
        #pragma unroll
        for (int j = 0; j < 8; ++j) acc[i][j] = 0.f;

    for (int kp0 = 0; kp0 < 80; kp0 += 16) {
        __syncthreads();
        #pragma unroll
        for (int m = 0; m < 8; ++m) {
            int e = m * 256 + tid;          // 0..2047
            int kw = e >> 7, gw = e & 127;
            wsh[kw][gw] = wbase[(kp0 + kw) * 1024 + gj0 + gw];
            int ke = e & 15, ge = e >> 4;
            esh[ke][ge] = emb16[((size_t)ge * L_ + t) * 80 + kp0 + ke];
        }
        __syncthreads();
        #pragma unroll
        for (int kp = 0; kp < 16; ++kp) {
            unsigned wv[8], ev[8];
            #pragma unroll
            for (int q = 0; q < 8; ++q) wv[q] = wsh[kp][ty * 8 + q];
            #pragma unroll
            for (int q = 0; q < 8; ++q) ev[q] = esh[kp][tx * 8 + q];
            #pragma unroll
            for (int i = 0; i < 8; ++i)
                #pragma unroll
                for (int j = 0; j < 8; ++j) acc[i][j] = fdot2_(wv[i], ev[j], acc[i][j]);
        }
    }
    #pragma unroll
    for (int i = 0; i < 8; ++i) {
        int gj = gj0 + ty * 8 + i;
        float bias = bi[gj] + bh[gj];
        #pragma unroll
        for (int j = 0; j < 8; ++j) {
            int b = tx * 8 + j;
            xg[((((size_t)dir * L_ + t) * 64 + (b >> 1)) * 1024 + gj) * 2 + (b & 1)]
                = acc[i][j] + bias;
        }
    }
}

// ---------------------------------------------------------------------------
// Phase 2: BiLSTM scan — R9 configuration exactly (SLDS=24, 477us verified).
// ---------------------------------------------------------------------------
__global__ void __launch_bounds__(1024, 4) lstm_scan_s(
    const float* __restrict__ xg, const uint4* __restrict__ wp16,
    float* __restrict__ xf2, float* __restrict__ xb2)
{
    int blk = blockIdx.x;
    int dir = blk >> 6;            // 0..1
    int bp  = blk & 63;            // b-pair index
    int tid = threadIdx.x;
    int h   = tid & 255;           // hidden unit
    int q   = tid >> 8;            // k-quarter 0..3 (wave-uniform)

    const uint4* wt = wp16 + (size_t)dir * 128 * 256;   // [p][hid] uint4
    float* xo = dir ? xb2 : xf2;

    __shared__ uint2 hA[128];            // [p] = {bs0 f16x2, bs1 f16x2}
    __shared__ uint2 hB[128];
    __shared__ float pbuf[4][8][256];    // [q][gate*2+bs][h], 32KB
    __shared__ uint4 wlds[SLDS][256];    // q0's p=0..SLDS-1, 96KB

    for (int m = q; m < SLDS; m += 4)
        wlds[m][h] = wt[m * 256 + h];

    if (tid < 256) ((unsigned*)hA)[tid] = 0u;
    float c0 = 0.f, c1 = 0.f;            // live only in q==0 threads
    __syncthreads();

    int pq0  = q * 32;
    int sbeg = (q == 0) ? SLDS : pq0;
    int send = pq0 + 32;

    for (int t = 0; t < L_; ++t) {
        int slot = dir ? (L_ - 1 - t) : t;
        const uint2* hp = (t & 1) ? hB : hA;
        unsigned*    hw = (unsigned*)((t & 1) ? hA : hB);

        float2 gI, gF, gG, gO;
        if (q == 0) {
            const float* xbase = xg + (((size_t)dir * L_ + slot) * 64 + bp) * 2048;
            gI = *(const float2*)(xbase + (0 * 256 + h) * 2);
            gF = *(const float2*)(xbase + (1 * 256 + h) * 2);
            gG = *(const float2*)(xbase + (2 * 256 + h) * 2);
            gO = *(const float2*)(xbase + (3 * 256 + h) * 2);
        }

        float aI0=0.f, aI1=0.f, aF0=0.f, aF1=0.f;
        float aG0=0.f, aG1=0.f, aO0=0.f, aO1=0.f;

        #pragma unroll 8
        for (int p = sbeg; p < send; ++p) {
            uint4 w4 = wt[p * 256 + h];   // coalesced 1KB/wave from L2
            uint2 hb = hp[p];             // broadcast b64
            aI0 = fdot2_(w4.x, hb.x, aI0); aI1 = fdot2_(w4.x, hb.y, aI1);
            aF0 = fdot2_(w4.y, hb.x, aF0); aF1 = fdot2_(w4.y, hb.y, aF1);
            aG0 = fdot2_(w4.z, hb.x, aG0); aG1 = fdot2_(w4.z, hb.y, aG1);
            aO0 = fdot2_(w4.w, hb.x, aO0); aO1 = fdot2_(w4.w, hb.y, aO1);
        }
        if (q == 0) {
            #pragma unroll 8
            for (int p = 0; p < SLDS; ++p) {
                uint4 w4 = wlds[p][h];
                uint2 hb = hp[p];
                aI0 = fdot2_(w4.x, hb.x, aI0); aI1 = fdot2_(w4.x, hb.y, aI1);
                aF0 = fdot2_(w4.y, hb.x, aF0); aF1 = fdot2_(w4.y, hb.y, aF1);
                aG0 = fdot2_(w4.z, hb.x, aG0); aG1 = fdot2_(w4.z, hb.y, aG1);
                aO0 = fdot2_(w4.w, hb.x, aO0); aO1 = fdot2_(w4.w, hb.y, aO1);
            }
        }

        pbuf[q][0][h] = aI0; pbuf[q][1][h] = aI1;
        pbuf[q][2][h] = aF0; pbuf[q][3][h] = aF1;
        pbuf[q][4][h] = aG0; pbuf[q][5][h] = aG1;
        pbuf[q][6][h] = aO0; pbuf[q][7][h] = aO1;
        __syncthreads();

        if (q == 0) {
            float sI0 = pbuf[0][0][h] + pbuf[1][0][h] + pbuf[2][0][h] + pbuf[3][0][h] + gI.x;
            float sI1 = pbuf[0][1][h] + pbuf[1][1][h] + pbuf[2][1][h] + pbuf[3][1][h] + gI.y;
            float sF0 = pbuf[0][2][h] + pbuf[1][2][h] + pbuf[2][2][h] + pbuf[3][2][h] + gF.x;
            float sF1 = pbuf[0][3][h] + pbuf[1][3][h] + pbuf[2][3][h] + pbuf[3][3][h] + gF.y;
            float sG0 = pbuf[0][4][h] + pbuf[1][4][h] + pbuf[2][4][h] + pbuf[3][4][h] + gG.x;
            float sG1 = pbuf[0][5][h] + pbuf[1][5][h] + pbuf[2][5][h] + pbuf[3][5][h] + gG.y;
            float sO0 = pbuf[0][6][h] + pbuf[1][6][h] + pbuf[2][6][h] + pbuf[3][6][h] + gO.x;
            float sO1 = pbuf[0][7][h] + pbuf[1][7][h] + pbuf[2][7][h] + pbuf[3][7][h] + gO.y;

            float i0 = 1.f / (1.f + expf(-sI0));
            float f0 = 1.f / (1.f + expf(-sF0));
            float g0 = tanhf(sG0);
            float o0 = 1.f / (1.f + expf(-sO0));
            c0 = f0 * c0 + i0 * g0;
            float hv0 = o0 * tanhf(c0);

            float i1 = 1.f / (1.f + expf(-sI1));
            float f1 = 1.f / (1.f + expf(-sF1));
            float g1 = tanhf(sG1);
            float o1 = 1.f / (1.f + expf(-sO1));
            c1 = f1 * c1 + i1 * g1;
            float hv1 = o1 * tanhf(c1);

            float n0 = __shfl_xor(hv0, 1);
            float n1 = __shfl_xor(hv1, 1);
            hw[h] = (h & 1) ? pack2(n1, hv1)
                            : pack2(hv0, n0);
            float* xp = xo + ((size_t)slot * 64 + bp) * 512 + h * 2;
            xp[0] = hv0; xp[1] = hv1;
        }
        __syncthreads();
    }
}

// remap [slot][bp][hid*2+bs] -> x[slot][hid][b], summing directions.
__global__ void x_add(const float* __restrict__ xf2, const float* __restrict__ xb2,
                      float* __restrict__ x)
{
    int idx = blockIdx.x * 256 + threadIdx.x;   // exactly L_*HID_*B_ threads
    int b    = idx & 127;
    int j    = (idx >> 7) & 255;
    int slot = idx >> 15;
    int src  = ((slot * 64 + (b >> 1)) * 512) + j * 2 + (b & 1);
    x[idx] = xf2[src] + xb2[src];
}

// ---------------------------------------------------------------------------
// Phase 2.5: pack W_caps to f16 c-pairs (unchanged).
// ---------------------------------------------------------------------------
__global__ void wc_pack16(const float* __restrict__ W, unsigned* __restrict__ wc)
{
    int gid = blockIdx.x * 256 + threadIdx.x;   // exactly 1600*8*304 threads
    int od  = gid % OD;
    int rest = gid / OD;
    int cp  = rest & 7;
    int i   = rest >> 3;
    float a = W[((size_t)i * 16 + 2 * cp) * OD + od];
    float b = W[((size_t)i * 16 + 2 * cp + 1) * OD + od];
    wc[gid] = pack2(a, b);
}

// ---------------------------------------------------------------------------
// Phase 3: attention chain (unchanged).
// ---------------------------------------------------------------------------
__global__ void compute_he2(const int* __restrict__ pos1, const int* __restrict__ pos2,
                            const float* __restrict__ x, float* __restrict__ he)
{
    int j = blockIdx.x, b = threadIdx.x;
    int e1 = 0, e2 = 0;
    for (int l = L_ - 1; l >= 0; --l) if (pos1[b * L_ + l] == ENTITY) e1 = l;
    for (int l = L_ - 1; l >= 0; --l) if (pos2[b * L_ + l] == ENTITY) e2 = l;
    he[j * B_ + b] = x[((size_t)e1 * HID_ + j) * B_ + b] + x[((size_t)e2 * HID_ + j) * B_ + b];
}

__global__ void att_logits2(const float* __restrict__ x, const float* __restrict__ he,
                            float* __restrict__ lp)
{
    int l = blockIdx.x, jc = blockIdx.y, b = threadIdx.x;
    int j0 = jc * 32;
    float acc = 0.f;
    #pragma unroll
    for (int jj = 0; jj < 32; ++jj) {
        int j = j0 + jj;
        acc = fmaf(x[((size_t)l * HID_ + j) * B_ + b], he[j * B_ + b], acc);
    }
    lp[((size_t)jc * L_ + l) * B_ + b] = acc;
}

__global__ void att_softmax2(const float* __restrict__ lp, float* __restrict__ att)
{
    int b = blockIdx.x, l = threadIdx.x;    // 128 blocks x 128 threads
    float val = 0.f;
    if (l < L_) {
        #pragma unroll
        for (int jc = 0; jc < 8; ++jc) val += lp[((size_t)jc * L_ + l) * B_ + b];
    }
    __shared__ float red[128];
    red[l] = (l < L_) ? val : -1e30f;
    __syncthreads();
    for (int off = 64; off > 0; off >>= 1) {
        if (l < off) red[l] = fmaxf(red[l], red[l + off]);
        __syncthreads();
    }
    float m = red[0];
    __syncthreads();
    float e = (l < L_) ? expf(val - m) : 0.f;
    red[l] = e;
    __syncthreads();
    for (int off = 64; off > 0; off >>= 1) {
        if (l < off) red[l] += red[l + off];
        __syncthreads();
    }
    float inv = 1.f / red[0];
    if (l < L_) att[l * B_ + b] = e * inv;
}

__global__ void u_squash16(const float* __restrict__ x, unsigned* __restrict__ u16)
{
    int i = blockIdx.x, b = threadIdx.x;
    int l = i >> 4, cap = i & 15;
    float vals[16]; float n2 = 0.f;
    #pragma unroll
    for (int c2 = 0; c2 < 16; ++c2) {
        float v = x[((size_t)l * HID_ + cap * 16 + c2) * B_ + b];
        vals[c2] = v; n2 = fmaf(v, v, n2);
    }
    float f = (n2 / (1.f + n2)) / sqrtf(n2 + 1e-9f);
    #pragma unroll
    for (int cp = 0; cp < 8; ++cp)
        u16[((size_t)i * B_ + b) * 8 + cp] = pack2(vals[2 * cp] * f, vals[2 * cp + 1] * f);
}

// ---------------------------------------------------------------------------
// Phase 4: routing — R11/R9 configuration (BLH=16, grid 100x8). R12's
// BLH=32 regressed (-250us): acc[32]/vv[32] register pressure + 40KB C-tile
// occupancy loss swamped the W-reuse gain. Rule: don't trade regs for bytes.
// ---------------------------------------------------------------------------
__global__ void __launch_bounds__(320) s_pass16(
    const unsigned* __restrict__ u16, const unsigned* __restrict__ Wc16,
    const float* __restrict__ bb, const float* __restrict__ br, int first,
    const float* __restrict__ att, float* __restrict__ partial)
{
    int ic = blockIdx.x, bt = blockIdx.y;
    int i0 = ic * 16, b0 = bt * BLH;
    __shared__ float C[BLH][16][20];   // [bl][il][o], padded
    int tid = threadIdx.x;
    for (int e = tid; e < BLH * 16; e += 320) {
        int bl = e >> 4, il = e & 15;
        int b = b0 + bl, i = i0 + il;
        const float* bbp = first ? (br + (size_t)i * NCLASS)
                                 : (bb + ((size_t)b * NI + i) * NCLASS);
        float m = bbp[0];
        #pragma unroll
        for (int o = 1; o < NCLASS; ++o) m = fmaxf(m, bbp[o]);
        float s = 0.f; float e2[NCLASS];
        #pragma unroll
        for (int o = 0; o < NCLASS; ++o) { e2[o] = expf(bbp[o] - m); s += e2[o]; }
        float al = att[(i >> 4) * B_ + b] / s;
        #pragma unroll
        for (int o = 0; o < NCLASS; ++o) C[bl][il][o] = e2[o] * al;
    }
    __syncthreads();
    if (tid >= OD) return;
    int od = tid, o = od >> 4;
    float acc[BLH];
    #pragma unroll
    for (int bl = 0; bl < BLH; ++bl) acc[bl] = 0.f;
    for (int il = 0; il < 16; ++il) {
        int i = i0 + il;
        const unsigned* wp = Wc16 + (size_t)i * 8 * OD + od;
        unsigned w2[8];
        #pragma unroll
        for (int cp = 0; cp < 8; ++cp) w2[cp] = wp[cp * OD];     // coalesced over od
        const unsigned* up = u16 + ((size_t)i * B_ + b0) * 8;    // uniform -> s_load
        #pragma unroll
        for (int bl = 0; bl < BLH; ++bl) {
            float uh = 0.f;
            #pragma unroll
            for (int cp = 0; cp < 8; ++cp) uh = fdot2_(up[bl * 8 + cp], w2[cp], uh);
            acc[bl] = fmaf(C[bl][il][o], uh, acc[bl]);
        }
    }
    #pragma unroll
    for (int bl = 0; bl < BLH; ++bl)
        partial[((size_t)ic * B_ + b0 + bl) * OD + od] = acc[bl];
}

// fused: sum partials over ic, squash to v, optional capsule-length output
__global__ void __launch_bounds__(320) sreduce_squash(
    const float* __restrict__ partial, float* __restrict__ v,
    float* __restrict__ out, int write_out)
{
    int b = blockIdx.x;            // 128 blocks
    int od = threadIdx.x;          // 320 threads, od < OD active
    if (od >= OD) return;
    float acc = 0.f;
    for (int ic = 0; ic < 100; ++ic) acc += partial[((size_t)ic * B_ + b) * OD + od];
    float n2 = acc * acc;
    n2 += __shfl_xor(n2, 1); n2 += __shfl_xor(n2, 2);
    n2 += __shfl_xor(n2, 4); n2 += __shfl_xor(n2, 8);
    float f = (n2 / (1.f + n2)) / sqrtf(n2 + 1e-9f);
    float vv = acc * f;
    v[(size_t)b * OD + od] = vv;
    if (write_out) {
        float n2v = vv * vv;
        n2v += __shfl_xor(n2v, 1); n2v += __shfl_xor(n2v, 2);
        n2v += __shfl_xor(n2v, 4); n2v += __shfl_xor(n2v, 8);
        if ((od & 15) == 0) out[b * NCLASS + (od >> 4)] = sqrtf(n2v + 1e-9f);
    }
}

__global__ void __launch_bounds__(320) bb_pass16(
    const unsigned* __restrict__ u16, const unsigned* __restrict__ Wc16,
    const float* __restrict__ v, float* __restrict__ bb,
    const float* __restrict__ br, int first)
{
    int ic = blockIdx.x, bt = blockIdx.y;
    int i0 = ic * 16, b0 = bt * BLH;
    int tid = threadIdx.x;
    if (tid >= OD) return;
    int od = tid, o = od >> 4, d = od & 15;
    float vv[BLH];
    #pragma unroll
    for (int bl = 0; bl < BLH; ++bl) vv[bl] = v[(size_t)(b0 + bl) * OD + od];
    for (int il = 0; il < 16; ++il) {
        int i = i0 + il;
        const unsigned* wp = Wc16 + (size_t)i * 8 * OD + od;
        unsigned w2[8];
        #pragma unroll
        for (int cp = 0; cp < 8; ++cp) w2[cp] = wp[cp * OD];
        const unsigned* up = u16 + ((size_t)i * B_ + b0) * 8;
        #pragma unroll
        for (int bl = 0; bl < BLH; ++bl) {
            float uh = 0.f;
            #pragma unroll
            for (int cp = 0; cp < 8; ++cp) uh = fdot2_(up[bl * 8 + cp], w2[cp], uh);
            float p = uh * vv[bl];
            p += __shfl_xor(p, 1);
            p += __shfl_xor(p, 2);
            p += __shfl_xor(p, 4);
            p += __shfl_xor(p, 8);
            if (d == 0) {
                size_t off = ((size_t)(b0 + bl) * NI + i) * NCLASS + o;
                bb[off] = (first ? br[(size_t)i * NCLASS + o] : bb[off]) + p;
            }
        }
    }
}

// ---------------------------------------------------------------------------
extern "C" void kernel_launch(void* const* d_in, const int* in_sizes, int n_in,
                              void* d_out, int out_size, void* d_ws, size_t ws_size,
                              hipStream_t stream)
{
    (void)in_sizes; (void)n_in; (void)out_size; (void)ws_size;
    const int*   word = (const int*)d_in[0];
    const int*   tag  = (const int*)d_in[1];
    const int*   pos1 = (const int*)d_in[2];
    const int*   pos2 = (const int*)d_in[3];
    const float* we   = (const float*)d_in[4];
    const float* te   = (const float*)d_in[5];
    const float* p1e  = (const float*)d_in[6];
    const float* p2e  = (const float*)d_in[7];
    const float* wihf = (const float*)d_in[8];
    const float* whhf = (const float*)d_in[9];
    const float* bihf = (const float*)d_in[10];
    const float* bhhf = (const float*)d_in[11];
    const float* wihb = (const float*)d_in[12];
    const float* whhb = (const float*)d_in[13];
    const float* bihb = (const float*)d_in[14];
    const float* bhhb = (const float*)d_in[15];
    const float* Wc   = (const float*)d_in[16];
    const float* br   = (const float*)d_in[17];

    float* wsp = (float*)d_ws;
    // packed-input region (old emb area, 2,048,000 floats):
    unsigned* emb16 = (unsigned*)wsp;                    // 1,024,000 uints
    unsigned* wih16 = (unsigned*)(wsp + 1024000);        //   163,840 uints
    unsigned* wp16  = (unsigned*)(wsp + 1024000 + 163840); // 262,144 uints
    float* xg  = wsp + 2048000;                // 26,214,400
    float* xf  = xg + 26214400;                //  3,276,800
    float* xb  = xf + 3276800;                 //  3,276,800
    float* he  = xb + 3276800;                 //     32,768
    float* att = he + 32768;                   //     12,800
    // packed f16 W_caps spans xf and part of xb (both dead after x_add)
    unsigned* Wc16 = (unsigned*)xf;            //  3,891,200 uints
    float*    lp   = xf + 3891200;             //    102,400 (xb tail, free)
    // post-scan buffers alias the (dead-after-scan) xg region
    float*    x    = xg;                       //  3,276,800
    unsigned* u16  = (unsigned*)(xg + 3276800);//  1,638,400 uints
    float*    bb   = xg + 6553600;             //  3,891,200
    float*    part = xg + 10444800;            //  3,891,200
    float*    s    = xg + 14336000;            //     38,912 (unused now)
    float*    v    = s + 38912;                //     38,912
    float*    out  = (float*)d_out;

    prep16<<<5665, 256, 0, stream>>>(word, tag, pos1, pos2, we, te, p1e, p2e,
                                     wihf, wihb, whhf, whhb, emb16, wih16, wp16);
    gemm_xg16<<<dim3(8, 100, 2), 256, 0, stream>>>(emb16, wih16, bihf, bhhf, bihb, bhhb, xg);
    lstm_scan_s<<<128, 1024, 0, stream>>>(xg, (const uint4*)wp16, xf, xb);
    x_add<<<12800, 256, 0, stream>>>(xf, xb, x);
    wc_pack16<<<15200, 256, 0, stream>>>(Wc, Wc16);   // after x_add: xf/xb dead
    compute_he2<<<256, 128, 0, stream>>>(pos1, pos2, x, he);
    att_logits2<<<dim3(100, 8), 128, 0, stream>>>(x, he, lp);
    att_softmax2<<<128, 128, 0, stream>>>(lp, att);
    u_squash16<<<1600, 128, 0, stream>>>(x, u16);
    for (int it = 0; it < 3; ++it) {
        s_pass16<<<dim3(100, NBT), 320, 0, stream>>>(u16, Wc16, bb, br, it == 0, att, part);
        sreduce_squash<<<128, 320, 0, stream>>>(part, v, out, (it == 2) ? 1 : 0);
        if (it < 2) bb_pass16<<<dim3(100, NBT), 320, 0, stream>>>(u16, Wc16, v, bb, br, it == 0);
    }
}